// Round 2
// baseline (123.493 us; speedup 1.0000x reference)
//
#include <hip/hip_runtime.h>
#include <math.h>

#define BB 4
#define NN 1024
#define MM 1024
#define HH 64
#define NCH 64            // n-chunks (partials) per (b,m)
#define CH (NN / NCH)     // 16 keys per chunk
#define NGROUPS 16        // (b, mtile) groups = BB * (MM/256)

static constexpr float NEG_BIG = -3.0e38f;
static constexpr float SCALE = -0.72134752044448170f;   // -0.5 * log2(e)

// ---------------- Kernel 1: fused prep ----------------
// grid 272 blocks x 256:
//   bx in [0,128)   : K-MLP   (rowblk = (bx&127)>>3, out-chunk = bx&7)
//   bx in [128,256) : Q-MLP
//   bx in [256,272) : vhat = V.Wo with Wo folded through the V-MLP; block 256 also zeroes ctr
__global__ __launch_bounds__(256)
void prep_kernel(const float* __restrict__ coords_f,
                 const float* __restrict__ values_f,
                 const float* __restrict__ coords_t,
                 const float* __restrict__ Wk1, const float* __restrict__ bk1,
                 const float* __restrict__ Wk2, const float* __restrict__ bk2,
                 const float* __restrict__ Wq1, const float* __restrict__ bq1,
                 const float* __restrict__ Wq2, const float* __restrict__ bq2,
                 const float* __restrict__ Wv1, const float* __restrict__ bv1,
                 const float* __restrict__ Wv2, const float* __restrict__ bv2,
                 const float* __restrict__ Wo,
                 float* __restrict__ Kout, float* __restrict__ Qout,
                 float* __restrict__ vhat, int* __restrict__ ctr) {
    const int bx = blockIdx.x;
    const int tid = threadIdx.x;

    if (bx < 256) {
        const int type = bx >> 7;            // 0 = K, 1 = Q
        const int sub = bx & 127;
        const int row = (sub >> 3) * 256 + tid;   // 0..4095
        const int co  = (sub & 7) * 8;            // output sub-chunk

        const float* in = type ? coords_t : coords_f;
        const float* W1 = type ? Wq1 : Wk1;
        const float* b1 = type ? bq1 : bk1;
        const float* W2 = type ? Wq2 : Wk2;
        const float* b2 = type ? bq2 : bk2;
        float* out = type ? Qout : Kout;

        const float in0 = in[row * 3 + 0];
        const float in1 = in[row * 3 + 1];
        const float in2 = in[row * 3 + 2];

        float acc[8];
#pragma unroll
        for (int j = 0; j < 8; ++j) acc[j] = b2[co + j];

        for (int hi = 0; hi < HH; ++hi) {
            float h = b1[hi];
            h = fmaf(in0, W1[hi], h);
            h = fmaf(in1, W1[64 + hi], h);
            h = fmaf(in2, W1[128 + hi], h);
            h = fmaxf(h, 0.0f);
            const float* w = W2 + hi * 64 + co;    // uniform -> scalar loads
#pragma unroll
            for (int j = 0; j < 8; ++j) acc[j] = fmaf(h, w[j], acc[j]);
        }
#pragma unroll
        for (int j = 0; j < 8; ++j) out[row * 64 + co + j] = acc[j];
    } else {
        const int sub = bx - 256;                 // 0..15
        if (sub == 0 && tid < NGROUPS) ctr[tid] = 0;

        __shared__ float w2o[64];
        __shared__ float b2o_sh;
        if (tid < 64) {
            float s = 0.0f;
            for (int ho = 0; ho < 64; ++ho) s = fmaf(Wv2[tid * 64 + ho], Wo[ho], s);
            w2o[tid] = s;
        }
        if (tid == 0) {
            float s = 0.0f;
            for (int ho = 0; ho < 64; ++ho) s = fmaf(bv2[ho], Wo[ho], s);
            b2o_sh = s;
        }
        __syncthreads();

        const int row = sub * 256 + tid;          // 0..4095
        const float* vin = values_f + row * 5;
        const float i0 = vin[0], i1 = vin[1], i2 = vin[2], i3 = vin[3], i4 = vin[4];

        float s = b2o_sh;
        for (int j = 0; j < HH; ++j) {
            float h = bv1[j];
            h = fmaf(i0, Wv1[j], h);
            h = fmaf(i1, Wv1[64 + j], h);
            h = fmaf(i2, Wv1[128 + j], h);
            h = fmaf(i3, Wv1[192 + j], h);
            h = fmaf(i4, Wv1[256 + j], h);
            h = fmaxf(h, 0.0f);
            s = fmaf(h, w2o[j], s);
        }
        vhat[row] = s;
    }
}

// ---------------- Kernel 2: dist + online softmax partials + last-block combine ----------------
// grid (MM/256, NCH, BB), block 256. Thread owns one m; Q[m,:] in 64 VGPRs.
// K chunk (16x64) staged in LDS, read with wave-uniform addresses (broadcast).
// Per-(b,mtile) atomic counter: the last of the 64 chunk-blocks combines the
// partials (fixed ascending-c order -> deterministic, identical to a separate pass).
__global__ __launch_bounds__(256)
void dist_kernel(const float* __restrict__ Kb,
                 const float* __restrict__ Qb,
                 const float* __restrict__ vh,
                 const float* __restrict__ bo,
                 float* __restrict__ mx_out,
                 float* __restrict__ den_out,
                 float* __restrict__ num_out,
                 int* __restrict__ ctr,
                 float* __restrict__ out) {
    __shared__ float kt[CH * 64];   // 4 KB
    __shared__ float vt[CH];
    __shared__ int sh_last;

    const int tid = threadIdx.x;
    const int b = blockIdx.z;
    const int c = blockIdx.y;
    const int mtile = blockIdx.x;
    const int m = mtile * 256 + tid;

    const float4* ksrc = reinterpret_cast<const float4*>(Kb + (b * NN + c * CH) * 64);
    reinterpret_cast<float4*>(kt)[tid] = ksrc[tid];
    if (tid < CH) vt[tid] = vh[b * NN + c * CH + tid];
    __syncthreads();

    float4 q[16];
    const float4* qsrc = reinterpret_cast<const float4*>(Qb + (b * MM + m) * 64);
#pragma unroll
    for (int i = 0; i < 16; ++i) q[i] = qsrc[i];

    float mx = NEG_BIG, den = 0.0f, num = 0.0f;

    for (int n = 0; n < CH; ++n) {
        const float4* kr = reinterpret_cast<const float4*>(kt + n * 64);
        float d0 = 0.0f, d1 = 0.0f, d2 = 0.0f, d3 = 0.0f;
#pragma unroll
        for (int i = 0; i < 16; ++i) {
            float4 k4 = kr[i];   // uniform LDS address -> broadcast, conflict-free
            d0 += fabsf(k4.x - q[i].x);
            d1 += fabsf(k4.y - q[i].y);
            d2 += fabsf(k4.z - q[i].z);
            d3 += fabsf(k4.w - q[i].w);
        }
        const float d = (d0 + d1) + (d2 + d3);
        const float a = d * d * SCALE;             // log2-domain score
        const float nm = fmaxf(mx, a);
        const float s0 = __builtin_amdgcn_exp2f(mx - nm);
        const float p  = __builtin_amdgcn_exp2f(a - nm);
        den = fmaf(den, s0, p);
        num = fmaf(num, s0, p * vt[n]);
        mx = nm;
    }

    const int bm = b * MM + m;
    const int pidx = c * (BB * MM) + bm;           // [c][bm] -> coalesced both ways
    mx_out[pidx]  = mx;
    den_out[pidx] = den;
    num_out[pidx] = num;

    // --- last-block-done combine ---
    __threadfence();                                // release our partials (device scope)
    __syncthreads();
    if (tid == 0) {
        const int g = b * 4 + mtile;
        int prev = atomicAdd(&ctr[g], 1);           // device-scope by default
        sh_last = (prev == NCH - 1) ? 1 : 0;
    }
    __syncthreads();
    if (sh_last) {
        __threadfence();                            // acquire all released partials
        float M = NEG_BIG, D = 0.0f, Nu = 0.0f;
        for (int cc = 0; cc < NCH; ++cc) {
            const int idx = cc * (BB * MM) + bm;
            const float mc = mx_out[idx];
            const float dc = den_out[idx];
            const float nc = num_out[idx];
            const float nm = fmaxf(M, mc);
            const float s0 = __builtin_amdgcn_exp2f(M - nm);
            const float s1 = __builtin_amdgcn_exp2f(mc - nm);
            D  = D * s0 + dc * s1;
            Nu = Nu * s0 + nc * s1;
            M = nm;
        }
        out[bm] = Nu / D + bo[0];
    }
}

// ---------------- launcher ----------------
extern "C" void kernel_launch(void* const* d_in, const int* in_sizes, int n_in,
                              void* d_out, int out_size, void* d_ws, size_t ws_size,
                              hipStream_t stream) {
    const float* coords_f = (const float*)d_in[0];
    const float* values_f = (const float*)d_in[1];
    const float* coords_t = (const float*)d_in[2];
    const float* Wk1 = (const float*)d_in[3];
    const float* bk1 = (const float*)d_in[4];
    const float* Wk2 = (const float*)d_in[5];
    const float* bk2 = (const float*)d_in[6];
    const float* Wq1 = (const float*)d_in[7];
    const float* bq1 = (const float*)d_in[8];
    const float* Wq2 = (const float*)d_in[9];
    const float* bq2 = (const float*)d_in[10];
    const float* Wv1 = (const float*)d_in[11];
    const float* bv1 = (const float*)d_in[12];
    const float* Wv2 = (const float*)d_in[13];
    const float* bv2 = (const float*)d_in[14];
    const float* Wo  = (const float*)d_in[15];
    const float* bo  = (const float*)d_in[16];

    float* ws  = (float*)d_ws;
    float* Kb  = ws;                      // B*N*H   = 262144
    float* Qb  = Kb + BB * NN * HH;       // B*M*H   = 262144
    float* vh  = Qb + BB * MM * HH;       // B*N     = 4096
    float* mx  = vh + BB * NN;            // B*M*NCH = 262144
    float* den = mx + BB * MM * NCH;
    float* num = den + BB * MM * NCH;
    int*   ctr = (int*)(num + BB * MM * NCH);   // 16 ints, zeroed by prep each launch

    prep_kernel<<<dim3(272), 256, 0, stream>>>(
        coords_f, values_f, coords_t,
        Wk1, bk1, Wk2, bk2, Wq1, bq1, Wq2, bq2,
        Wv1, bv1, Wv2, bv2, Wo, Kb, Qb, vh, ctr);

    dist_kernel<<<dim3(MM / 256, NCH, BB), 256, 0, stream>>>(
        Kb, Qb, vh, bo, mx, den, num, ctr, (float*)d_out);
}

// Round 3
// 35.673 us; speedup vs baseline: 3.4618x; 3.4618x over previous
//
#include <hip/hip_runtime.h>
#include <math.h>

#define BB 4
#define NN 1024
#define MM 1024
#define HH 64
#define NT 8              // n-tiles
#define BN 128            // n per block
#define BM 64             // m per block
#define MT (MM / BM)      // 16 m-tiles

static constexpr float NEG_BIG = -3.0e38f;
static constexpr float SCALE = -0.72134752044448170f;   // -0.5 * log2(e)

// ---------------- Kernel 1: fused prep (K-MLP, Q-MLP, vhat = V.Wo) ----------------
// grid 272 x 256. bx<128: K-MLP; 128..255: Q-MLP; 256..271: vhat.
__global__ __launch_bounds__(256)
void prep_kernel(const float* __restrict__ coords_f,
                 const float* __restrict__ values_f,
                 const float* __restrict__ coords_t,
                 const float* __restrict__ Wk1, const float* __restrict__ bk1,
                 const float* __restrict__ Wk2, const float* __restrict__ bk2,
                 const float* __restrict__ Wq1, const float* __restrict__ bq1,
                 const float* __restrict__ Wq2, const float* __restrict__ bq2,
                 const float* __restrict__ Wv1, const float* __restrict__ bv1,
                 const float* __restrict__ Wv2, const float* __restrict__ bv2,
                 const float* __restrict__ Wo,
                 float* __restrict__ Kout, float* __restrict__ Qout,
                 float* __restrict__ vhat) {
    const int bx = blockIdx.x;
    const int tid = threadIdx.x;

    if (bx < 256) {
        const int type = bx >> 7;                 // 0 = K, 1 = Q
        const int sub = bx & 127;
        const int row = (sub >> 3) * 256 + tid;   // 0..4095
        const int co  = (sub & 7) * 8;

        const float* in = type ? coords_t : coords_f;
        const float* W1 = type ? Wq1 : Wk1;
        const float* b1 = type ? bq1 : bk1;
        const float* W2 = type ? Wq2 : Wk2;
        const float* b2 = type ? bq2 : bk2;
        float* out = type ? Qout : Kout;

        const float in0 = in[row * 3 + 0];
        const float in1 = in[row * 3 + 1];
        const float in2 = in[row * 3 + 2];

        float acc[8];
#pragma unroll
        for (int j = 0; j < 8; ++j) acc[j] = b2[co + j];

        for (int hi = 0; hi < HH; ++hi) {
            float h = b1[hi];
            h = fmaf(in0, W1[hi], h);
            h = fmaf(in1, W1[64 + hi], h);
            h = fmaf(in2, W1[128 + hi], h);
            h = fmaxf(h, 0.0f);
            const float* w = W2 + hi * 64 + co;
#pragma unroll
            for (int j = 0; j < 8; ++j) acc[j] = fmaf(h, w[j], acc[j]);
        }
#pragma unroll
        for (int j = 0; j < 8; ++j) out[row * 64 + co + j] = acc[j];
    } else {
        const int sub = bx - 256;                 // 0..15
        __shared__ float w2o[64];
        __shared__ float b2o_sh;
        if (tid < 64) {
            float s = 0.0f;
            for (int ho = 0; ho < 64; ++ho) s = fmaf(Wv2[tid * 64 + ho], Wo[ho], s);
            w2o[tid] = s;
        }
        if (tid == 0) {
            float s = 0.0f;
            for (int ho = 0; ho < 64; ++ho) s = fmaf(bv2[ho], Wo[ho], s);
            b2o_sh = s;
        }
        __syncthreads();

        const int row = sub * 256 + tid;
        const float* vin = values_f + row * 5;
        const float i0 = vin[0], i1 = vin[1], i2 = vin[2], i3 = vin[3], i4 = vin[4];

        float s = b2o_sh;
        for (int j = 0; j < HH; ++j) {
            float h = bv1[j];
            h = fmaf(i0, Wv1[j], h);
            h = fmaf(i1, Wv1[64 + j], h);
            h = fmaf(i2, Wv1[128 + j], h);
            h = fmaf(i3, Wv1[192 + j], h);
            h = fmaf(i4, Wv1[256 + j], h);
            h = fmaxf(h, 0.0f);
            s = fmaf(h, w2o[j], s);
        }
        vhat[row] = s;
    }
}

// ---------------- Kernel 2: GEMM-tiled L1-dist + in-block softmax partials ----------------
// grid (NT=8, MT=16, BB=4) = 512 blocks, 256 threads.
// Block: 128n x 64m tile. Thread (ty=tid/16, tx=tid%16): 8n x 4m register tile,
//   n = n0 + ni*16 + ty, m = m0 + mj*16 + tx.
// K/Q tiles in LDS, XOR-swizzled (float4 col ^= row&7) -> conflict-free reads.
__global__ __launch_bounds__(256)
void fused_kernel(const float* __restrict__ Kb,
                  const float* __restrict__ Qb,
                  const float* __restrict__ vh,
                  float* __restrict__ mxp,
                  float* __restrict__ denp,
                  float* __restrict__ nump) {
    __shared__ float kt[BN * 64];   // 32 KB, swizzled; reused as reduction buffer
    __shared__ float qt[BM * 64];   // 16 KB, swizzled

    const int tid = threadIdx.x;
    const int nt = blockIdx.x, mt = blockIdx.y, b = blockIdx.z;
    const int n0 = nt * BN, m0 = mt * BM;
    const int ty = tid >> 4, tx = tid & 15;

    float4* kt4 = reinterpret_cast<float4*>(kt);
    float4* qt4 = reinterpret_cast<float4*>(qt);

    // stage K tile: 128x64 floats = 2048 float4, 8 per thread
    {
        const float4* ksrc = reinterpret_cast<const float4*>(Kb + (b * NN + n0) * 64);
#pragma unroll
        for (int l = 0; l < 8; ++l) {
            const int fidx = l * 256 + tid;
            const int row = fidx >> 4, h4 = fidx & 15;
            kt4[row * 16 + (h4 ^ (row & 7))] = ksrc[fidx];
        }
        // stage Q tile: 64x64 floats = 1024 float4, 4 per thread
        const float4* qsrc = reinterpret_cast<const float4*>(Qb + (b * MM + m0) * 64);
#pragma unroll
        for (int l = 0; l < 4; ++l) {
            const int fidx = l * 256 + tid;
            const int row = fidx >> 4, h4 = fidx & 15;
            qt4[row * 16 + (h4 ^ (row & 7))] = qsrc[fidx];
        }
    }
    __syncthreads();

    const int swk = ty & 7;   // row swizzle for this thread's k rows (ni*16+ty)
    const int swq = tx & 7;   // row swizzle for this thread's q rows (mj*16+tx)

    float acc[8][4];
#pragma unroll
    for (int i = 0; i < 8; ++i)
#pragma unroll
        for (int j = 0; j < 4; ++j) acc[i][j] = 0.0f;

#pragma unroll 4
    for (int h4 = 0; h4 < 16; ++h4) {
        float4 kv[8], qv[4];
#pragma unroll
        for (int ni = 0; ni < 8; ++ni)
            kv[ni] = kt4[(ni * 16 + ty) * 16 + (h4 ^ swk)];
#pragma unroll
        for (int mj = 0; mj < 4; ++mj)
            qv[mj] = qt4[(mj * 16 + tx) * 16 + (h4 ^ swq)];
#pragma unroll
        for (int ni = 0; ni < 8; ++ni)
#pragma unroll
            for (int mj = 0; mj < 4; ++mj) {
                acc[ni][mj] += fabsf(kv[ni].x - qv[mj].x);
                acc[ni][mj] += fabsf(kv[ni].y - qv[mj].y);
                acc[ni][mj] += fabsf(kv[ni].z - qv[mj].z);
                acc[ni][mj] += fabsf(kv[ni].w - qv[mj].w);
            }
    }

    // per-thread online softmax over its 8 n's, for each of its 4 m's
    float vloc[8];
#pragma unroll
    for (int ni = 0; ni < 8; ++ni) vloc[ni] = vh[b * NN + n0 + ni * 16 + ty];

    float mxr[4], denr[4], numr[4];
#pragma unroll
    for (int mj = 0; mj < 4; ++mj) {
        float mx = NEG_BIG, den = 0.0f, num = 0.0f;
#pragma unroll
        for (int ni = 0; ni < 8; ++ni) {
            const float d = acc[ni][mj];
            const float a = d * d * SCALE;
            const float nm = fmaxf(mx, a);
            const float s0 = __builtin_amdgcn_exp2f(mx - nm);
            const float p  = __builtin_amdgcn_exp2f(a - nm);
            den = fmaf(den, s0, p);
            num = fmaf(num, s0, p * vloc[ni]);
            mx = nm;
        }
        mxr[mj] = mx; denr[mj] = den; numr[mj] = num;
    }

    // cross-thread (over ty) reduction in LDS: red[ty][mcol][3], aliases kt
    __syncthreads();          // all kt reads done
    float* red = kt;          // 16*64*3 = 3072 floats = 12 KB
#pragma unroll
    for (int mj = 0; mj < 4; ++mj) {
        const int base = (ty * 64 + mj * 16 + tx) * 3;
        red[base + 0] = mxr[mj];
        red[base + 1] = denr[mj];
        red[base + 2] = numr[mj];
    }
    __syncthreads();

    if (tid < 64) {           // one thread per m-col
        float M = NEG_BIG, D = 0.0f, Nu = 0.0f;
        for (int t = 0; t < 16; ++t) {
            const int base = (t * 64 + tid) * 3;
            const float m2 = red[base + 0];
            const float d2 = red[base + 1];
            const float n2 = red[base + 2];
            const float nm = fmaxf(M, m2);
            const float s0 = __builtin_amdgcn_exp2f(M - nm);
            const float s1 = __builtin_amdgcn_exp2f(m2 - nm);
            D  = D * s0 + d2 * s1;
            Nu = Nu * s0 + n2 * s1;
            M = nm;
        }
        const int p = nt * (BB * MM) + b * MM + m0 + tid;
        mxp[p] = M; denp[p] = D; nump[p] = Nu;
    }
}

// ---------------- Kernel 3: combine n-tile partials ----------------
// grid 16 x 256: thread per (b,m).
__global__ __launch_bounds__(256)
void combine_kernel(const float* __restrict__ mxp,
                    const float* __restrict__ denp,
                    const float* __restrict__ nump,
                    const float* __restrict__ bo,
                    float* __restrict__ out) {
    const int bm = blockIdx.x * 256 + threadIdx.x;   // b*MM + m
    float M = NEG_BIG, D = 0.0f, Nu = 0.0f;
#pragma unroll
    for (int nt = 0; nt < NT; ++nt) {
        const int idx = nt * (BB * MM) + bm;
        const float m2 = mxp[idx];
        const float d2 = denp[idx];
        const float n2 = nump[idx];
        const float nm = fmaxf(M, m2);
        const float s0 = __builtin_amdgcn_exp2f(M - nm);
        const float s1 = __builtin_amdgcn_exp2f(m2 - nm);
        D  = D * s0 + d2 * s1;
        Nu = Nu * s0 + n2 * s1;
        M = nm;
    }
    out[bm] = Nu / D + bo[0];
}

// ---------------- launcher ----------------
extern "C" void kernel_launch(void* const* d_in, const int* in_sizes, int n_in,
                              void* d_out, int out_size, void* d_ws, size_t ws_size,
                              hipStream_t stream) {
    const float* coords_f = (const float*)d_in[0];
    const float* values_f = (const float*)d_in[1];
    const float* coords_t = (const float*)d_in[2];
    const float* Wk1 = (const float*)d_in[3];
    const float* bk1 = (const float*)d_in[4];
    const float* Wk2 = (const float*)d_in[5];
    const float* bk2 = (const float*)d_in[6];
    const float* Wq1 = (const float*)d_in[7];
    const float* bq1 = (const float*)d_in[8];
    const float* Wq2 = (const float*)d_in[9];
    const float* bq2 = (const float*)d_in[10];
    const float* Wv1 = (const float*)d_in[11];
    const float* bv1 = (const float*)d_in[12];
    const float* Wv2 = (const float*)d_in[13];
    const float* bv2 = (const float*)d_in[14];
    const float* Wo  = (const float*)d_in[15];
    const float* bo  = (const float*)d_in[16];

    float* ws  = (float*)d_ws;
    float* Kb  = ws;                      // B*N*H = 262144
    float* Qb  = Kb + BB * NN * HH;       // 262144
    float* vh  = Qb + BB * MM * HH;       // 4096
    float* mxp = vh + BB * NN;            // NT*B*M = 32768
    float* denp = mxp + NT * BB * MM;
    float* nump = denp + NT * BB * MM;

    prep_kernel<<<dim3(272), 256, 0, stream>>>(
        coords_f, values_f, coords_t,
        Wk1, bk1, Wk2, bk2, Wq1, bq1, Wq2, bq2,
        Wv1, bv1, Wv2, bv2, Wo, Kb, Qb, vh);

    fused_kernel<<<dim3(NT, MT, BB), 256, 0, stream>>>(
        Kb, Qb, vh, mxp, denp, nump);

    combine_kernel<<<dim3(16), 256, 0, stream>>>(
        mxp, denp, nump, bo, (float*)d_out);
}

// Round 4
// 35.350 us; speedup vs baseline: 3.4934x; 1.0091x over previous
//
#include <hip/hip_runtime.h>
#include <math.h>

#define BB 4
#define NN 1024
#define MM 1024
#define HH 64
#define NT 8              // n-tiles
#define BN 128            // n per block
#define BM 64             // m per block
#define MT (MM / BM)      // 16 m-tiles

static constexpr float NEG_BIG = -3.0e38f;
static constexpr float SCALE = -0.72134752044448170f;   // -0.5 * log2(e)

// ---------------- Kernel 1: fused prep (K-MLP, Q-MLP, vhat = V.Wo) ----------------
__global__ __launch_bounds__(256)
void prep_kernel(const float* __restrict__ coords_f,
                 const float* __restrict__ values_f,
                 const float* __restrict__ coords_t,
                 const float* __restrict__ Wk1, const float* __restrict__ bk1,
                 const float* __restrict__ Wk2, const float* __restrict__ bk2,
                 const float* __restrict__ Wq1, const float* __restrict__ bq1,
                 const float* __restrict__ Wq2, const float* __restrict__ bq2,
                 const float* __restrict__ Wv1, const float* __restrict__ bv1,
                 const float* __restrict__ Wv2, const float* __restrict__ bv2,
                 const float* __restrict__ Wo,
                 float* __restrict__ Kout, float* __restrict__ Qout,
                 float* __restrict__ vhat) {
    const int bx = blockIdx.x;
    const int tid = threadIdx.x;

    if (bx < 256) {
        const int type = bx >> 7;                 // 0 = K, 1 = Q
        const int sub = bx & 127;
        const int row = (sub >> 3) * 256 + tid;   // 0..4095
        const int co  = (sub & 7) * 8;

        const float* in = type ? coords_t : coords_f;
        const float* W1 = type ? Wq1 : Wk1;
        const float* b1 = type ? bq1 : bk1;
        const float* W2 = type ? Wq2 : Wk2;
        const float* b2 = type ? bq2 : bk2;
        float* out = type ? Qout : Kout;

        const float in0 = in[row * 3 + 0];
        const float in1 = in[row * 3 + 1];
        const float in2 = in[row * 3 + 2];

        float acc[8];
#pragma unroll
        for (int j = 0; j < 8; ++j) acc[j] = b2[co + j];

        for (int hi = 0; hi < HH; ++hi) {
            float h = b1[hi];
            h = fmaf(in0, W1[hi], h);
            h = fmaf(in1, W1[64 + hi], h);
            h = fmaf(in2, W1[128 + hi], h);
            h = fmaxf(h, 0.0f);
            const float* w = W2 + hi * 64 + co;    // uniform -> scalar loads
#pragma unroll
            for (int j = 0; j < 8; ++j) acc[j] = fmaf(h, w[j], acc[j]);
        }
#pragma unroll
        for (int j = 0; j < 8; ++j) out[row * 64 + co + j] = acc[j];
    } else {
        const int sub = bx - 256;                 // 0..15
        __shared__ float w2o[64];
        __shared__ float b2o_sh;
        if (tid < 64) {
            float s = 0.0f;
            for (int ho = 0; ho < 64; ++ho) s = fmaf(Wv2[tid * 64 + ho], Wo[ho], s);
            w2o[tid] = s;
        }
        if (tid == 0) {
            float s = 0.0f;
            for (int ho = 0; ho < 64; ++ho) s = fmaf(bv2[ho], Wo[ho], s);
            b2o_sh = s;
        }
        __syncthreads();

        const int row = sub * 256 + tid;
        const float* vin = values_f + row * 5;
        const float i0 = vin[0], i1 = vin[1], i2 = vin[2], i3 = vin[3], i4 = vin[4];

        float s = b2o_sh;
        for (int j = 0; j < HH; ++j) {
            float h = bv1[j];
            h = fmaf(i0, Wv1[j], h);
            h = fmaf(i1, Wv1[64 + j], h);
            h = fmaf(i2, Wv1[128 + j], h);
            h = fmaf(i3, Wv1[192 + j], h);
            h = fmaf(i4, Wv1[256 + j], h);
            h = fmaxf(h, 0.0f);
            s = fmaf(h, w2o[j], s);
        }
        vhat[row] = s;
    }
}

// ---------------- Kernel 2: GEMM-tiled L1-dist + in-block softmax partials ----------------
// grid (NT=8, MT=16, BB=4) = 512 blocks, 256 threads.
// Block: 128n x 64m. Thread (ty=tid/16, tx=tid%16): 8n x 4m register tile.
// K/Q tiles LDS, XOR-swizzled float4 columns -> conflict-free (2-way max, free).
__global__ __launch_bounds__(256)
void fused_kernel(const float* __restrict__ Kb,
                  const float* __restrict__ Qb,
                  const float* __restrict__ vh,
                  float* __restrict__ mxp,
                  float* __restrict__ denp,
                  float* __restrict__ nump) {
    __shared__ float kt[BN * 64];   // 32 KB, swizzled; reused as reduction buffer
    __shared__ float qt[BM * 64];   // 16 KB, swizzled

    const int tid = threadIdx.x;
    const int nt = blockIdx.x, mt = blockIdx.y, b = blockIdx.z;
    const int n0 = nt * BN, m0 = mt * BM;
    const int ty = tid >> 4, tx = tid & 15;

    float4* kt4 = reinterpret_cast<float4*>(kt);
    float4* qt4 = reinterpret_cast<float4*>(qt);

    {
        const float4* ksrc = reinterpret_cast<const float4*>(Kb + (b * NN + n0) * 64);
#pragma unroll
        for (int l = 0; l < 8; ++l) {
            const int fidx = l * 256 + tid;
            const int row = fidx >> 4, h4 = fidx & 15;
            kt4[row * 16 + (h4 ^ (row & 7))] = ksrc[fidx];
        }
        const float4* qsrc = reinterpret_cast<const float4*>(Qb + (b * MM + m0) * 64);
#pragma unroll
        for (int l = 0; l < 4; ++l) {
            const int fidx = l * 256 + tid;
            const int row = fidx >> 4, h4 = fidx & 15;
            qt4[row * 16 + (h4 ^ (row & 7))] = qsrc[fidx];
        }
    }
    __syncthreads();

    const int swk = ty & 7;
    const int swq = tx & 7;

    float acc[8][4];
#pragma unroll
    for (int i = 0; i < 8; ++i)
#pragma unroll
        for (int j = 0; j < 4; ++j) acc[i][j] = 0.0f;

#pragma unroll 2
    for (int h4 = 0; h4 < 16; ++h4) {
        float4 kv[8], qv[4];
#pragma unroll
        for (int ni = 0; ni < 8; ++ni)
            kv[ni] = kt4[(ni * 16 + ty) * 16 + (h4 ^ swk)];
#pragma unroll
        for (int mj = 0; mj < 4; ++mj)
            qv[mj] = qt4[(mj * 16 + tx) * 16 + (h4 ^ swq)];
#pragma unroll
        for (int ni = 0; ni < 8; ++ni)
#pragma unroll
            for (int mj = 0; mj < 4; ++mj) {
                acc[ni][mj] += fabsf(kv[ni].x - qv[mj].x);
                acc[ni][mj] += fabsf(kv[ni].y - qv[mj].y);
                acc[ni][mj] += fabsf(kv[ni].z - qv[mj].z);
                acc[ni][mj] += fabsf(kv[ni].w - qv[mj].w);
            }
    }

    // per-thread two-pass softmax over its 8 n's, for each of its 4 m's
    float vloc[8];
#pragma unroll
    for (int ni = 0; ni < 8; ++ni) vloc[ni] = vh[b * NN + n0 + ni * 16 + ty];

    float mxr[4], denr[4], numr[4];
#pragma unroll
    for (int mj = 0; mj < 4; ++mj) {
        float a[8];
        float sc[8];
#pragma unroll
        for (int ni = 0; ni < 8; ++ni) {
            const float d = acc[ni][mj];
            sc[ni] = d * SCALE;                       // d*S
            a[ni] = d * sc[ni];                       // d^2 * S  (log2-domain score)
        }
        float mx = fmaxf(fmaxf(fmaxf(a[0], a[1]), fmaxf(a[2], a[3])),
                         fmaxf(fmaxf(a[4], a[5]), fmaxf(a[6], a[7])));
        float den = 0.0f, num = 0.0f;
#pragma unroll
        for (int ni = 0; ni < 8; ++ni) {
            const float p = __builtin_amdgcn_exp2f(a[ni] - mx);
            den += p;
            num = fmaf(p, vloc[ni], num);
        }
        mxr[mj] = mx; denr[mj] = den; numr[mj] = num;
    }

    // cross-thread (over ty) reduction in LDS
    __syncthreads();
    float* red = kt;          // 16*64*3 floats = 12 KB, aliases kt
#pragma unroll
    for (int mj = 0; mj < 4; ++mj) {
        const int base = (ty * 64 + mj * 16 + tx) * 3;
        red[base + 0] = mxr[mj];
        red[base + 1] = denr[mj];
        red[base + 2] = numr[mj];
    }
    __syncthreads();

    if (tid < 64) {
        float M = NEG_BIG, D = 0.0f, Nu = 0.0f;
        for (int t = 0; t < 16; ++t) {
            const int base = (t * 64 + tid) * 3;
            const float m2 = red[base + 0];
            const float d2 = red[base + 1];
            const float n2 = red[base + 2];
            const float nm = fmaxf(M, m2);
            const float s0 = __builtin_amdgcn_exp2f(M - nm);
            const float s1 = __builtin_amdgcn_exp2f(m2 - nm);
            D  = D * s0 + d2 * s1;
            Nu = Nu * s0 + n2 * s1;
            M = nm;
        }
        const int p = nt * (BB * MM) + b * MM + m0 + tid;
        mxp[p] = M; denp[p] = D; nump[p] = Nu;
    }
}

// ---------------- Kernel 3: combine n-tile partials ----------------
// grid 64 x 64: thread per (b,m), spread across more CUs.
__global__ __launch_bounds__(64)
void combine_kernel(const float* __restrict__ mxp,
                    const float* __restrict__ denp,
                    const float* __restrict__ nump,
                    const float* __restrict__ bo,
                    float* __restrict__ out) {
    const int bm = blockIdx.x * 64 + threadIdx.x;   // b*MM + m
    float M = NEG_BIG, D = 0.0f, Nu = 0.0f;
#pragma unroll
    for (int nt = 0; nt < NT; ++nt) {
        const int idx = nt * (BB * MM) + bm;
        const float m2 = mxp[idx];
        const float d2 = denp[idx];
        const float n2 = nump[idx];
        const float nm = fmaxf(M, m2);
        const float s0 = __builtin_amdgcn_exp2f(M - nm);
        const float s1 = __builtin_amdgcn_exp2f(m2 - nm);
        D  = D * s0 + d2 * s1;
        Nu = Nu * s0 + n2 * s1;
        M = nm;
    }
    out[bm] = Nu / D + bo[0];
}

// ---------------- launcher ----------------
extern "C" void kernel_launch(void* const* d_in, const int* in_sizes, int n_in,
                              void* d_out, int out_size, void* d_ws, size_t ws_size,
                              hipStream_t stream) {
    const float* coords_f = (const float*)d_in[0];
    const float* values_f = (const float*)d_in[1];
    const float* coords_t = (const float*)d_in[2];
    const float* Wk1 = (const float*)d_in[3];
    const float* bk1 = (const float*)d_in[4];
    const float* Wk2 = (const float*)d_in[5];
    const float* bk2 = (const float*)d_in[6];
    const float* Wq1 = (const float*)d_in[7];
    const float* bq1 = (const float*)d_in[8];
    const float* Wq2 = (const float*)d_in[9];
    const float* bq2 = (const float*)d_in[10];
    const float* Wv1 = (const float*)d_in[11];
    const float* bv1 = (const float*)d_in[12];
    const float* Wv2 = (const float*)d_in[13];
    const float* bv2 = (const float*)d_in[14];
    const float* Wo  = (const float*)d_in[15];
    const float* bo  = (const float*)d_in[16];

    float* ws  = (float*)d_ws;
    float* Kb  = ws;                      // B*N*H = 262144
    float* Qb  = Kb + BB * NN * HH;       // 262144
    float* vh  = Qb + BB * MM * HH;       // 4096
    float* mxp = vh + BB * NN;            // NT*B*M = 32768
    float* denp = mxp + NT * BB * MM;
    float* nump = denp + NT * BB * MM;

    prep_kernel<<<dim3(272), 256, 0, stream>>>(
        coords_f, values_f, coords_t,
        Wk1, bk1, Wk2, bk2, Wq1, bq1, Wq2, bq2,
        Wv1, bv1, Wv2, bv2, Wo, Kb, Qb, vh);

    fused_kernel<<<dim3(NT, MT, BB), 256, 0, stream>>>(
        Kb, Qb, vh, mxp, denp, nump);

    combine_kernel<<<dim3(64), 64, 0, stream>>>(
        mxp, denp, nump, bo, (float*)d_out);
}